// Round 4
// baseline (836.308 us; speedup 1.0000x reference)
//
#include <hip/hip_runtime.h>
#include <stdint.h>

// problem dims
#define T_B 128
#define T_N 512
#define T_D 512
#define T_C 256
#define T_S 500
#define T_K 4

// workspace offsets (bytes)
#define OFF_H        0ull            // 65536*256 f32 (64 MiB)
#define OFF_W1P      67108864ull     // 512*256 f32
#define OFF_ROWSTAT  67633152ull     // 65536 float2
#define OFF_U        68157440ull     // 256 f32
#define OFF_V        68158464ull     // 256 f32
#define OFF_GTERM    68159488ull     // 128*256 f32
#define OFF_SCORE    68290560ull     // 65536 f32
#define OFF_COUNTS   68552704ull     // 128*4*512 i32 (1 MiB)
#define OFF_CLSPOS   69601280ull     // 128 i32

// ---------------- device helpers ----------------
__device__ __forceinline__ float gelu_exact(float z) {
  return 0.5f * z * (1.0f + erff(z * 0.70710678118654752440f));
}

// JAX threefry2x32, key = (0, 12345)
__device__ __forceinline__ uint2 threefry2x32(uint32_t x0, uint32_t x1) {
  const uint32_t k0 = 0u;
  const uint32_t k1 = 12345u;
  const uint32_t k2 = k0 ^ k1 ^ 0x1BD11BDAu;
  x0 += k0; x1 += k1;
#define TF_ROUND(r) { x0 += x1; x1 = (x1 << (r)) | (x1 >> (32 - (r))); x1 ^= x0; }
  TF_ROUND(13) TF_ROUND(15) TF_ROUND(26) TF_ROUND(6)
  x0 += k1; x1 += k2 + 1u;
  TF_ROUND(17) TF_ROUND(29) TF_ROUND(16) TF_ROUND(24)
  x0 += k2; x1 += k0 + 2u;
  TF_ROUND(13) TF_ROUND(15) TF_ROUND(26) TF_ROUND(6)
  x0 += k0; x1 += k1 + 3u;
  TF_ROUND(17) TF_ROUND(29) TF_ROUND(16) TF_ROUND(24)
  x0 += k1; x1 += k2 + 4u;
  TF_ROUND(13) TF_ROUND(15) TF_ROUND(26) TF_ROUND(6)
  x0 += k2; x1 += k0 + 5u;
#undef TF_ROUND
  return make_uint2(x0, x1);
}

// JAX uniform(lo=nextafter(-1,0), hi=1) bit pipeline for f32
__device__ __forceinline__ float bits_to_u(uint32_t bits) {
  float f = __uint_as_float((bits >> 9) | 0x3F800000u) - 1.0f;
  float u = f * 2.0f - 0.99999994f;     // (hi-lo) rounds to 2.0f; *2 exact -> contraction-safe
  return fmaxf(-0.99999994f, u);
}

// XLA ErfInv32 (Giles poly, w = -log1p(-x*x))
__device__ __forceinline__ float erfinv_f(float x) {
  float w = -log1pf(-x * x);
  float p;
  if (w < 5.0f) {
    w = w - 2.5f;
    p = 2.81022636e-08f;
    p = fmaf(p, w, 3.43273939e-07f);
    p = fmaf(p, w, -3.5233877e-06f);
    p = fmaf(p, w, -4.39150654e-06f);
    p = fmaf(p, w, 0.00021858087f);
    p = fmaf(p, w, -0.00125372503f);
    p = fmaf(p, w, -0.00417768164f);
    p = fmaf(p, w, 0.246640727f);
    p = fmaf(p, w, 1.50140941f);
  } else {
    w = sqrtf(w) - 3.0f;
    p = -0.000200214257f;
    p = fmaf(p, w, 0.000100950558f);
    p = fmaf(p, w, 0.00134934322f);
    p = fmaf(p, w, -0.00367342844f);
    p = fmaf(p, w, 0.00573950773f);
    p = fmaf(p, w, -0.0076224613f);
    p = fmaf(p, w, 0.00943887047f);
    p = fmaf(p, w, 1.00167406f);
    p = fmaf(p, w, 2.83297682f);
  }
  return p * x;
}

// iterative top-4 over one wave holding 512 values (8/lane at n = j*64+lane).
// tie-break: equal value -> lower index (lax.top_k stable semantics).
__device__ __forceinline__ void top4_wave(float v[8], const int lane, int idx[4]) {
#pragma unroll
  for (int it = 0; it < 4; it++) {
    float bv = -INFINITY;
    int bn = 0x7FFFFFFF;
#pragma unroll
    for (int j = 0; j < 8; j++) {
      const int n = (j << 6) + lane;
      const bool better = (v[j] > bv) || ((v[j] == bv) && (n < bn));
      bv = better ? v[j] : bv;
      bn = better ? n : bn;
    }
#pragma unroll
    for (int m = 32; m >= 1; m >>= 1) {
      const float ov = __shfl_xor(bv, m);
      const int   on = __shfl_xor(bn, m);
      const bool better = (ov > bv) || ((ov == bv) && (on < bn));
      bv = better ? ov : bv;
      bn = better ? on : bn;
    }
    idx[it] = bn;
    const int jj = bn >> 6;
    const bool own = (bn & 63) == lane;
#pragma unroll
    for (int j = 0; j < 8; j++)
      if (own && j == jj) v[j] = -INFINITY;   // static index, no scratch
  }
}

__device__ __forceinline__ void sort4(int a[4]) {
#define CS(x, y) { int lo = min(a[x], a[y]); int hi = max(a[x], a[y]); a[x] = lo; a[y] = hi; }
  CS(0, 1) CS(2, 3) CS(0, 2) CS(1, 3) CS(1, 2)
#undef CS
}

// ---------------- kernels ----------------

// per-row mean / rstd of x (65536 rows of 512)
__global__ __launch_bounds__(256) void rowstats_kernel(const float* __restrict__ x,
                                                       float2* __restrict__ rowstat) {
  const int lane = threadIdx.x & 63;
  const int row = blockIdx.x * 4 + (threadIdx.x >> 6);
  const float* xr = x + (size_t)row * 512;
  float vals[8];
  float s = 0.0f;
#pragma unroll
  for (int j = 0; j < 8; j++) { vals[j] = xr[j * 64 + lane]; s += vals[j]; }
#pragma unroll
  for (int m = 1; m < 64; m <<= 1) s += __shfl_xor(s, m);
  const float mu = s * (1.0f / 512.0f);
  float d2 = 0.0f;
#pragma unroll
  for (int j = 0; j < 8; j++) { float d = vals[j] - mu; d2 = fmaf(d, d, d2); }
#pragma unroll
  for (int m = 1; m < 64; m <<= 1) d2 += __shfl_xor(d2, m);
  const float var = d2 * (1.0f / 512.0f);
  if (lane == 0) rowstat[row] = make_float2(mu, rsqrtf(var + 1e-5f));
}

// W1p[d,c] = ln_w[d] * w1[d,c]
__global__ __launch_bounds__(256) void w1p_kernel(const float* __restrict__ w1,
                                                  const float* __restrict__ lnw,
                                                  float* __restrict__ W1p) {
  const int d = blockIdx.x;
  const int c = threadIdx.x;
  W1p[d * 256 + c] = lnw[d] * w1[d * 256 + c];
}

// u[c] = sum_d ln_w[d] w1[d,c];  v[c] = sum_d ln_b[d] w1[d,c]
__global__ __launch_bounds__(256) void uv_kernel(const float* __restrict__ w1,
                                                 const float* __restrict__ lnw,
                                                 const float* __restrict__ lnb,
                                                 float* __restrict__ uvec,
                                                 float* __restrict__ vvec) {
  const int c = threadIdx.x;
  float u = 0.0f, v = 0.0f;
  for (int d = 0; d < 512; d++) {
    const float w = w1[d * 256 + c];
    u = fmaf(lnw[d], w, u);
    v = fmaf(lnb[d], w, v);
  }
  uvec[c] = u;
  vvec[c] = v;
}

// cls_pos[b] = argmax(ids[b,:]) (first max); also write out[b,0,:] = x[b,cls_pos,:]
__global__ __launch_bounds__(64) void clspos_kernel(const int* __restrict__ ids,
                                                    const float* __restrict__ x,
                                                    int* __restrict__ cls_pos,
                                                    float* __restrict__ out) {
  const int b = blockIdx.x;
  const int lane = threadIdx.x;
  unsigned long long best = 0ull;
#pragma unroll
  for (int j = 0; j < 8; j++) {
    const int n = j * 64 + lane;
    const unsigned v = (unsigned)ids[b * 512 + n];
    const unsigned long long key = ((unsigned long long)v << 32) | (unsigned)(511 - n);
    best = key > best ? key : best;
  }
#pragma unroll
  for (int m = 1; m < 64; m <<= 1) {
    const unsigned long long o = __shfl_xor(best, m);
    best = o > best ? o : best;
  }
  const int n = 511 - (int)(best & 0xFFFFFFFFu);
  if (lane == 0) cls_pos[b] = n;
  const float* xr = x + ((size_t)b * 512 + n) * 512;
  float* orow = out + (size_t)b * 2560;
#pragma unroll
  for (int j = 0; j < 8; j++) orow[j * 64 + lane] = xr[j * 64 + lane];
}

// GEMM1: h = gelu( rstd*(x@W1p - mu*u) + v + b1 )   (65536x512 @ 512x256)
__global__ __launch_bounds__(256) void gemm1_kernel(const float* __restrict__ A,
                                                    const float* __restrict__ Bm,
                                                    const float2* __restrict__ rowstat,
                                                    const float* __restrict__ uvec,
                                                    const float* __restrict__ vvec,
                                                    const float* __restrict__ b1,
                                                    float* __restrict__ H) {
  __shared__ float As[16][68];     // [k][row], padded
  __shared__ float Bs[16][256];    // [k][col]
  const int tid = threadIdx.x;
  const int tc = tid & 31;
  const int tr = tid >> 5;
  const int row0 = blockIdx.x * 64;
  float acc[8][8];
#pragma unroll
  for (int i = 0; i < 8; i++)
#pragma unroll
    for (int j = 0; j < 8; j++) acc[i][j] = 0.0f;

  const int kl = tid & 15;
  const int rb = tid >> 4;
  for (int kt = 0; kt < 512; kt += 16) {
#pragma unroll
    for (int i = 0; i < 4; i++) {
      const int rl = rb + i * 16;
      As[kl][rl] = A[(size_t)(row0 + rl) * 512 + kt + kl];
    }
#pragma unroll
    for (int j = 0; j < 16; j++) Bs[j][tid] = Bm[(kt + j) * 256 + tid];
    __syncthreads();
#pragma unroll
    for (int kk = 0; kk < 16; kk++) {
      float a[8], bf[8];
      *(float4*)&a[0] = *(const float4*)&As[kk][tr * 8];
      *(float4*)&a[4] = *(const float4*)&As[kk][tr * 8 + 4];
#pragma unroll
      for (int j = 0; j < 8; j++) bf[j] = Bs[kk][tc + 32 * j];
#pragma unroll
      for (int i = 0; i < 8; i++)
#pragma unroll
        for (int j = 0; j < 8; j++) acc[i][j] = fmaf(a[i], bf[j], acc[i][j]);
    }
    __syncthreads();
  }
  float uu[8], vv[8];
#pragma unroll
  for (int j = 0; j < 8; j++) {
    const int c = tc + 32 * j;
    uu[j] = uvec[c];
    vv[j] = vvec[c] + b1[c];
  }
#pragma unroll
  for (int i = 0; i < 8; i++) {
    const int r = row0 + tr * 8 + i;
    const float2 st = rowstat[r];
#pragma unroll
    for (int j = 0; j < 8; j++) {
      const float z = st.y * (acc[i][j] - st.x * uu[j]) + vv[j];
      H[(size_t)r * 256 + tc + 32 * j] = gelu_exact(z);
    }
  }
}

// gterm[b,c] = h[b,cls_pos[b],:] @ w2[256:512, c]
__global__ __launch_bounds__(256) void gterm_kernel(const float* __restrict__ H,
                                                    const float* __restrict__ W2,
                                                    const int* __restrict__ cls_pos,
                                                    float* __restrict__ gterm) {
  __shared__ float g[256];
  const int b = blockIdx.x;
  const int t = threadIdx.x;
  const int r = b * 512 + cls_pos[b];
  g[t] = H[(size_t)r * 256 + t];
  __syncthreads();
  float acc = 0.0f;
  for (int j = 0; j < 256; j++) acc = fmaf(g[j], W2[(256 + j) * 256 + t], acc);
  gterm[b * 256 + t] = acc;
}

// GEMM2 + epilogue: score[r] = sigmoid( sum_c gelu(h@w2_top + gterm) * w3[c] ) * mask_new
__global__ __launch_bounds__(256) void gemm2_kernel(const float* __restrict__ A,
                                                    const float* __restrict__ W2,
                                                    const float* __restrict__ gterm,
                                                    const float* __restrict__ w3,
                                                    const float* __restrict__ amask,
                                                    float* __restrict__ score) {
  __shared__ float As[16][68];
  __shared__ float Bs[16][256];
  const int tid = threadIdx.x;
  const int tc = tid & 31;
  const int tr = tid >> 5;
  const int row0 = blockIdx.x * 64;
  const int b = row0 >> 9;
  float acc[8][8];
#pragma unroll
  for (int i = 0; i < 8; i++)
#pragma unroll
    for (int j = 0; j < 8; j++) acc[i][j] = 0.0f;

  const int kl = tid & 15;
  const int rb = tid >> 4;
  for (int kt = 0; kt < 256; kt += 16) {
#pragma unroll
    for (int i = 0; i < 4; i++) {
      const int rl = rb + i * 16;
      As[kl][rl] = A[(size_t)(row0 + rl) * 256 + kt + kl];
    }
#pragma unroll
    for (int j = 0; j < 16; j++) Bs[j][tid] = W2[(kt + j) * 256 + tid];
    __syncthreads();
#pragma unroll
    for (int kk = 0; kk < 16; kk++) {
      float a[8], bf[8];
      *(float4*)&a[0] = *(const float4*)&As[kk][tr * 8];
      *(float4*)&a[4] = *(const float4*)&As[kk][tr * 8 + 4];
#pragma unroll
      for (int j = 0; j < 8; j++) bf[j] = Bs[kk][tc + 32 * j];
#pragma unroll
      for (int i = 0; i < 8; i++)
#pragma unroll
        for (int j = 0; j < 8; j++) acc[i][j] = fmaf(a[i], bf[j], acc[i][j]);
    }
    __syncthreads();
  }
  float w3v[8], gt[8];
#pragma unroll
  for (int j = 0; j < 8; j++) {
    const int c = tc + 32 * j;
    w3v[j] = w3[c];
    gt[j] = gterm[b * 256 + c];
  }
#pragma unroll
  for (int i = 0; i < 8; i++) {
    float s = 0.0f;
#pragma unroll
    for (int j = 0; j < 8; j++) {
      const float z = acc[i][j] + gt[j];
      s = fmaf(gelu_exact(z), w3v[j], s);
    }
#pragma unroll
    for (int m = 1; m < 32; m <<= 1) s += __shfl_xor(s, m);
    if (tc == 0) {
      const int r = row0 + tr * 8 + i;
      const int n = r & 511;
      const float mk = (n < 511) ? amask[(r >> 9) * 512 + n + 1] : 0.0f;
      score[r] = mk / (1.0f + expf(-s));
    }
  }
}

// perturbed top-k, JAX partitionable threefry:
// element i (flat over (B,S,N)) : bits = o0^o1 of threefry((0,12345),(0,i))
// one wave per sample (b,s); 64000 waves
__global__ __launch_bounds__(256) void topk_kernel(const float* __restrict__ score,
                                                   int* __restrict__ counts) {
  const int lane = threadIdx.x & 63;
  const int wid = threadIdx.x >> 6;
  const int p = blockIdx.x * 4 + wid;   // 0..63999  (= b*500 + s)
  const int b = p / 500;
  const uint32_t ibase = (uint32_t)p * 512u;
  const float* sc = score + b * 512;

  float v[8];
#pragma unroll
  for (int j = 0; j < 8; j++) {
    const int n = (j << 6) + lane;
    const uint2 o = threefry2x32(0u, ibase + (uint32_t)n);
    const uint32_t bits = o.x ^ o.y;
    const float nz = 1.41421356f * erfinv_f(bits_to_u(bits));
    v[j] = sc[n] + nz * 0.05f;
  }
  int idx[4];
  top4_wave(v, lane, idx);
  sort4(idx);
  if (lane == 0) {
    const int base = b * (T_K * T_N);
#pragma unroll
    for (int k = 0; k < 4; k++)
      atomicAdd(&counts[base + k * 512 + idx[k]], 1);
  }
}

// out[b,1+k,:] = (counts[b,k,:]/500) @ x[b,:,:]
__global__ __launch_bounds__(256) void select_kernel(const int* __restrict__ counts,
                                                     const float* __restrict__ x,
                                                     float* __restrict__ out) {
  __shared__ float cnt[4][512];
  __shared__ int list[512];
  __shared__ int nlist;
  const int b = blockIdx.x;
  const int t = threadIdx.x;
  if (t == 0) nlist = 0;
  __syncthreads();
  for (int l = t; l < 512; l += 256) {
    const int base = b * 2048 + l;
    const int c0 = counts[base];
    const int c1 = counts[base + 512];
    const int c2 = counts[base + 1024];
    const int c3 = counts[base + 1536];
    cnt[0][l] = (float)c0 * (1.0f / 500.0f);
    cnt[1][l] = (float)c1 * (1.0f / 500.0f);
    cnt[2][l] = (float)c2 * (1.0f / 500.0f);
    cnt[3][l] = (float)c3 * (1.0f / 500.0f);
    if ((c0 | c1 | c2 | c3) != 0) {
      const int pos = atomicAdd(&nlist, 1);
      list[pos] = l;
    }
  }
  __syncthreads();
  const int L = nlist;
  float a0[4] = {0.f, 0.f, 0.f, 0.f};
  float a1[4] = {0.f, 0.f, 0.f, 0.f};
  for (int e = 0; e < L; e++) {
    const int l = list[e];
    const float x0 = x[((size_t)b * 512 + l) * 512 + t];
    const float x1 = x[((size_t)b * 512 + l) * 512 + t + 256];
#pragma unroll
    for (int k = 0; k < 4; k++) {
      const float c = cnt[k][l];
      a0[k] = fmaf(c, x0, a0[k]);
      a1[k] = fmaf(c, x1, a1[k]);
    }
  }
#pragma unroll
  for (int k = 0; k < 4; k++) {
    out[(size_t)b * 2560 + (k + 1) * 512 + t] = a0[k];
    out[(size_t)b * 2560 + (k + 1) * 512 + t + 256] = a1[k];
  }
}

// ---------------- launcher ----------------
extern "C" void kernel_launch(void* const* d_in, const int* in_sizes, int n_in,
                              void* d_out, int out_size, void* d_ws, size_t ws_size,
                              hipStream_t stream) {
  const float* x     = (const float*)d_in[0];
  const int*   ids   = (const int*)d_in[1];
  const float* amask = (const float*)d_in[2];
  const float* lnw   = (const float*)d_in[3];
  const float* lnb   = (const float*)d_in[4];
  const float* w1    = (const float*)d_in[5];
  const float* b1    = (const float*)d_in[6];
  const float* w2    = (const float*)d_in[7];
  const float* w3    = (const float*)d_in[8];
  float* out = (float*)d_out;
  char* ws = (char*)d_ws;

  float*  H       = (float*)(ws + OFF_H);
  float*  W1p     = (float*)(ws + OFF_W1P);
  float2* rowstat = (float2*)(ws + OFF_ROWSTAT);
  float*  uvec    = (float*)(ws + OFF_U);
  float*  vvec    = (float*)(ws + OFF_V);
  float*  gterm   = (float*)(ws + OFF_GTERM);
  float*  score   = (float*)(ws + OFF_SCORE);
  int*    counts  = (int*)(ws + OFF_COUNTS);
  int*    clspos  = (int*)(ws + OFF_CLSPOS);

  rowstats_kernel<<<16384, 256, 0, stream>>>(x, rowstat);
  w1p_kernel<<<512, 256, 0, stream>>>(w1, lnw, W1p);
  uv_kernel<<<1, 256, 0, stream>>>(w1, lnw, lnb, uvec, vvec);
  clspos_kernel<<<128, 64, 0, stream>>>(ids, x, clspos, out);
  gemm1_kernel<<<1024, 256, 0, stream>>>(x, W1p, rowstat, uvec, vvec, b1, H);
  gterm_kernel<<<128, 256, 0, stream>>>(H, w2, clspos, gterm);
  gemm2_kernel<<<1024, 256, 0, stream>>>(H, w2, gterm, w3, amask, score);
  hipMemsetAsync(counts, 0, 128 * 4 * 512 * sizeof(int), stream);
  topk_kernel<<<16000, 256, 0, stream>>>(score, counts);
  select_kernel<<<128, 256, 0, stream>>>(counts, x, out);
}

// Round 6
// 681.078 us; speedup vs baseline: 1.2279x; 1.2279x over previous
//
#include <hip/hip_runtime.h>
#include <stdint.h>

// problem dims
#define T_B 128
#define T_N 512
#define T_D 512
#define T_C 256
#define T_S 500
#define T_K 4

// workspace offsets (bytes)
#define OFF_HP       0ull            // 65536x256 u32 (hi|lo<<16), quad-row tiled, 64 MiB
#define OFF_W1HT     67108864ull     // 256x512 bf16 (w1p^T hi)
#define OFF_W1LT     67371008ull     // 256x512 bf16 (w1p^T lo)
#define OFF_W2HT     67633152ull     // 256x256 bf16 (w2top^T hi)
#define OFF_W2LT     67764224ull     // 256x256 bf16 (w2top^T lo)
#define OFF_ROWSTAT  67895296ull     // 65536 float2
#define OFF_U        68419584ull     // 256 f32
#define OFF_V        68420608ull     // 256 f32
#define OFF_GTERM    68421632ull     // 128x256 f32
#define OFF_SCORE    68552704ull     // 65536 f32
#define OFF_CLSPOS   68814848ull     // 128 i32
#define OFF_COUNTS   0ull            // overlays HP: used only after gemm2/gterm done

typedef __attribute__((ext_vector_type(8))) short bf16x8;
typedef __attribute__((ext_vector_type(4))) float f32x4;

union BF8 { uint32_t u[4]; bf16x8 v; };

// ---------------- device helpers ----------------
__device__ __forceinline__ float gelu_exact(float z) {
  return 0.5f * z * (1.0f + erff(z * 0.70710678118654752440f));
}

__device__ __forceinline__ uint32_t rne_bf16(float f) {
  uint32_t u = __float_as_uint(f);
  return (u + 0x7FFFu + ((u >> 16) & 1u)) >> 16;
}

// JAX threefry2x32, key = (0, 12345)
__device__ __forceinline__ uint2 threefry2x32(uint32_t x0, uint32_t x1) {
  const uint32_t k0 = 0u;
  const uint32_t k1 = 12345u;
  const uint32_t k2 = k0 ^ k1 ^ 0x1BD11BDAu;
  x0 += k0; x1 += k1;
#define TF_ROUND(r) { x0 += x1; x1 = (x1 << (r)) | (x1 >> (32 - (r))); x1 ^= x0; }
  TF_ROUND(13) TF_ROUND(15) TF_ROUND(26) TF_ROUND(6)
  x0 += k1; x1 += k2 + 1u;
  TF_ROUND(17) TF_ROUND(29) TF_ROUND(16) TF_ROUND(24)
  x0 += k2; x1 += k0 + 2u;
  TF_ROUND(13) TF_ROUND(15) TF_ROUND(26) TF_ROUND(6)
  x0 += k0; x1 += k1 + 3u;
  TF_ROUND(17) TF_ROUND(29) TF_ROUND(16) TF_ROUND(24)
  x0 += k1; x1 += k2 + 4u;
  TF_ROUND(13) TF_ROUND(15) TF_ROUND(26) TF_ROUND(6)
  x0 += k2; x1 += k0 + 5u;
#undef TF_ROUND
  return make_uint2(x0, x1);
}

__device__ __forceinline__ float bits_to_u(uint32_t bits) {
  float f = __uint_as_float((bits >> 9) | 0x3F800000u) - 1.0f;
  float u = f * 2.0f - 0.99999994f;
  return fmaxf(-0.99999994f, u);
}

// XLA ErfInv32
__device__ __forceinline__ float erfinv_f(float x) {
  float w = -log1pf(-x * x);
  float p;
  if (w < 5.0f) {
    w = w - 2.5f;
    p = 2.81022636e-08f;
    p = fmaf(p, w, 3.43273939e-07f);
    p = fmaf(p, w, -3.5233877e-06f);
    p = fmaf(p, w, -4.39150654e-06f);
    p = fmaf(p, w, 0.00021858087f);
    p = fmaf(p, w, -0.00125372503f);
    p = fmaf(p, w, -0.00417768164f);
    p = fmaf(p, w, 0.246640727f);
    p = fmaf(p, w, 1.50140941f);
  } else {
    w = sqrtf(w) - 3.0f;
    p = -0.000200214257f;
    p = fmaf(p, w, 0.000100950558f);
    p = fmaf(p, w, 0.00134934322f);
    p = fmaf(p, w, -0.00367342844f);
    p = fmaf(p, w, 0.00573950773f);
    p = fmaf(p, w, -0.0076224613f);
    p = fmaf(p, w, 0.00943887047f);
    p = fmaf(p, w, 1.00167406f);
    p = fmaf(p, w, 2.83297682f);
  }
  return p * x;
}

__device__ __forceinline__ void top4_wave(float v[8], const int lane, int idx[4]) {
#pragma unroll
  for (int it = 0; it < 4; it++) {
    float bv = -INFINITY;
    int bn = 0x7FFFFFFF;
#pragma unroll
    for (int j = 0; j < 8; j++) {
      const int n = (j << 6) + lane;
      const bool better = (v[j] > bv) || ((v[j] == bv) && (n < bn));
      bv = better ? v[j] : bv;
      bn = better ? n : bn;
    }
#pragma unroll
    for (int m = 32; m >= 1; m >>= 1) {
      const float ov = __shfl_xor(bv, m);
      const int   on = __shfl_xor(bn, m);
      const bool better = (ov > bv) || ((ov == bv) && (on < bn));
      bv = better ? ov : bv;
      bn = better ? on : bn;
    }
    idx[it] = bn;
    const int jj = bn >> 6;
    const bool own = (bn & 63) == lane;
#pragma unroll
    for (int j = 0; j < 8; j++)
      if (own && j == jj) v[j] = -INFINITY;
  }
}

__device__ __forceinline__ void sort4(int a[4]) {
#define CS(x, y) { int lo = min(a[x], a[y]); int hi = max(a[x], a[y]); a[x] = lo; a[y] = hi; }
  CS(0, 1) CS(2, 3) CS(0, 2) CS(1, 3) CS(1, 2)
#undef CS
}

// ---------------- kernels ----------------

__global__ __launch_bounds__(256) void rowstats_kernel(const float* __restrict__ x,
                                                       float2* __restrict__ rowstat) {
  const int lane = threadIdx.x & 63;
  const int row = blockIdx.x * 4 + (threadIdx.x >> 6);
  const float* xr = x + (size_t)row * 512;
  float vals[8];
  float s = 0.0f;
#pragma unroll
  for (int j = 0; j < 8; j++) { vals[j] = xr[j * 64 + lane]; s += vals[j]; }
#pragma unroll
  for (int m = 1; m < 64; m <<= 1) s += __shfl_xor(s, m);
  const float mu = s * (1.0f / 512.0f);
  float d2 = 0.0f;
#pragma unroll
  for (int j = 0; j < 8; j++) { float d = vals[j] - mu; d2 = fmaf(d, d, d2); }
#pragma unroll
  for (int m = 1; m < 64; m <<= 1) d2 += __shfl_xor(d2, m);
  const float var = d2 * (1.0f / 512.0f);
  if (lane == 0) rowstat[row] = make_float2(mu, rsqrtf(var + 1e-5f));
}

// split + transpose weights: w1hT/w1lT[c][d] = split(lnw[d]*w1[d][c]); w2hT/w2lT[c][k] = split(w2[k][c])
__global__ __launch_bounds__(256) void prep_kernel(const float* __restrict__ w1,
                                                   const float* __restrict__ lnw,
                                                   const float* __restrict__ w2,
                                                   ushort* __restrict__ w1hT,
                                                   ushort* __restrict__ w1lT,
                                                   ushort* __restrict__ w2hT,
                                                   ushort* __restrict__ w2lT) {
  const int c = blockIdx.x;
  const int t = threadIdx.x;
#pragma unroll
  for (int it = 0; it < 2; it++) {
    const int d = t + it * 256;
    const float f = lnw[d] * w1[d * 256 + c];
    const uint32_t hi = rne_bf16(f);
    const float lo = f - __uint_as_float(hi << 16);
    w1hT[c * 512 + d] = (ushort)hi;
    w1lT[c * 512 + d] = (ushort)rne_bf16(lo);
  }
  {
    const float f = w2[t * 256 + c];   // top half of w2: k = t < 256
    const uint32_t hi = rne_bf16(f);
    const float lo = f - __uint_as_float(hi << 16);
    w2hT[c * 256 + t] = (ushort)hi;
    w2lT[c * 256 + t] = (ushort)rne_bf16(lo);
  }
}

__global__ __launch_bounds__(256) void uv_kernel(const float* __restrict__ w1,
                                                 const float* __restrict__ lnw,
                                                 const float* __restrict__ lnb,
                                                 float* __restrict__ uvec,
                                                 float* __restrict__ vvec) {
  const int c = threadIdx.x;
  float u = 0.0f, v = 0.0f;
  for (int d = 0; d < 512; d++) {
    const float w = w1[d * 256 + c];
    u = fmaf(lnw[d], w, u);
    v = fmaf(lnb[d], w, v);
  }
  uvec[c] = u;
  vvec[c] = v;
}

__global__ __launch_bounds__(64) void clspos_kernel(const int* __restrict__ ids,
                                                    const float* __restrict__ x,
                                                    int* __restrict__ cls_pos,
                                                    float* __restrict__ out) {
  const int b = blockIdx.x;
  const int lane = threadIdx.x;
  unsigned long long best = 0ull;
#pragma unroll
  for (int j = 0; j < 8; j++) {
    const int n = j * 64 + lane;
    const unsigned v = (unsigned)ids[b * 512 + n];
    const unsigned long long key = ((unsigned long long)v << 32) | (unsigned)(511 - n);
    best = key > best ? key : best;
  }
#pragma unroll
  for (int m = 1; m < 64; m <<= 1) {
    const unsigned long long o = __shfl_xor(best, m);
    best = o > best ? o : best;
  }
  const int n = 511 - (int)(best & 0xFFFFFFFFu);
  if (lane == 0) cls_pos[b] = n;
  const float* xr = x + ((size_t)b * 512 + n) * 512;
  float* orow = out + (size_t)b * 2560;
#pragma unroll
  for (int j = 0; j < 8; j++) orow[j * 64 + lane] = xr[j * 64 + lane];
}

// GEMM1 (MFMA, split-bf16): acc = x @ W1p; z = rstd*(acc - mu*u) + v + b1; Hp = split(gelu(z))
// grid 512 blocks x 256 thr; block tile 128 rows x 256 cols; waves 2x2 (wm, wn)
__global__ __launch_bounds__(256, 2) void gemm1_mfma(const float* __restrict__ x,
                                                     const ushort* __restrict__ w1hT,
                                                     const ushort* __restrict__ w1lT,
                                                     const float2* __restrict__ rowstat,
                                                     const float* __restrict__ uvec,
                                                     const float* __restrict__ vvec,
                                                     const float* __restrict__ b1,
                                                     uint32_t* __restrict__ Hp) {
  const int l = threadIdx.x & 63;
  const int wid = threadIdx.x >> 6;
  const int wm = wid >> 1, wn = wid & 1;
  const int lr = l & 15;
  const int g  = l >> 4;
  const int row0 = blockIdx.x * 128;

  f32x4 acc[4][8];
#pragma unroll
  for (int mt = 0; mt < 4; mt++)
#pragma unroll
    for (int nt = 0; nt < 8; nt++) acc[mt][nt] = (f32x4)0.0f;

  const float* xb = x + (size_t)(row0 + wm * 64 + lr) * 512 + g * 8;
  const ushort* bhb = w1hT + (size_t)(wn * 128 + lr) * 512 + g * 8;
  const ushort* blb = w1lT + (size_t)(wn * 128 + lr) * 512 + g * 8;

  for (int kt = 0; kt < 16; kt++) {
    const int ko = kt * 32;
    bf16x8 ah[4], al[4];
#pragma unroll
    for (int mt = 0; mt < 4; mt++) {
      const float4 f0 = *(const float4*)(xb + (size_t)mt * 16 * 512 + ko);
      const float4 f1 = *(const float4*)(xb + (size_t)mt * 16 * 512 + ko + 4);
      float f[8] = {f0.x, f0.y, f0.z, f0.w, f1.x, f1.y, f1.z, f1.w};
      BF8 H, L;
#pragma unroll
      for (int p = 0; p < 4; p++) {
        const uint32_t u0 = __float_as_uint(f[2 * p]);
        const uint32_t u1 = __float_as_uint(f[2 * p + 1]);
        H.u[p] = (u0 >> 16) | (u1 & 0xFFFF0000u);                 // trunc-hi pair
        const float l0 = f[2 * p]     - __uint_as_float(u0 & 0xFFFF0000u);
        const float l1 = f[2 * p + 1] - __uint_as_float(u1 & 0xFFFF0000u);
        L.u[p] = rne_bf16(l0) | (rne_bf16(l1) << 16);             // rne-lo pair
      }
      ah[mt] = H.v; al[mt] = L.v;
    }
#pragma unroll
    for (int nt = 0; nt < 8; nt++) {
      const bf16x8 bh = *(const bf16x8*)(bhb + (size_t)nt * 16 * 512 + ko);
      const bf16x8 bl = *(const bf16x8*)(blb + (size_t)nt * 16 * 512 + ko);
#pragma unroll
      for (int mt = 0; mt < 4; mt++) {
        acc[mt][nt] = __builtin_amdgcn_mfma_f32_16x16x32_bf16(ah[mt], bh, acc[mt][nt], 0, 0, 0);
        acc[mt][nt] = __builtin_amdgcn_mfma_f32_16x16x32_bf16(al[mt], bh, acc[mt][nt], 0, 0, 0);
        acc[mt][nt] = __builtin_amdgcn_mfma_f32_16x16x32_bf16(ah[mt], bl, acc[mt][nt], 0, 0, 0);
      }
    }
  }

  // epilogue: LN fold + gelu + split-store (4 rows per dwordx4)
#pragma unroll
  for (int mt = 0; mt < 4; mt++) {
    const int Rb = row0 + wm * 64 + mt * 16 + g * 4;   // 4 consecutive rows Rb..Rb+3
    float2 st[4];
#pragma unroll
    for (int r = 0; r < 4; r++) st[r] = rowstat[Rb + r];
#pragma unroll
    for (int nt = 0; nt < 8; nt++) {
      const int c = wn * 128 + nt * 16 + lr;
      const float uu = uvec[c];
      const float vvb = vvec[c] + b1[c];
      uint32_t pk[4];
#pragma unroll
      for (int r = 0; r < 4; r++) {
        const float z = st[r].y * (acc[mt][nt][r] - st[r].x * uu) + vvb;
        const float gg = gelu_exact(z);
        const uint32_t ug = __float_as_uint(gg);
        const uint32_t hi = ug >> 16;                              // trunc-hi
        const float lo = gg - __uint_as_float(ug & 0xFFFF0000u);
        pk[r] = hi | (rne_bf16(lo) << 16);
      }
      uint32_t* dst = Hp + (size_t)(Rb >> 2) * 1024 + c * 4;
      *(uint4*)dst = make_uint4(pk[0], pk[1], pk[2], pk[3]);
    }
  }
}

// gterm[b,c] = h[b,cls_pos[b],:] @ w2[256:512, c]   (h reconstructed = hi + lo)
__global__ __launch_bounds__(256) void gterm_kernel(const uint32_t* __restrict__ Hp,
                                                    const float* __restrict__ W2,
                                                    const int* __restrict__ cls_pos,
                                                    float* __restrict__ gterm) {
  __shared__ float gsh[256];
  const int b = blockIdx.x;
  const int t = threadIdx.x;
  const int r = b * 512 + cls_pos[b];
  const uint32_t u = Hp[(size_t)(r >> 2) * 1024 + t * 4 + (r & 3)];
  gsh[t] = __uint_as_float((u & 0xFFFFu) << 16) + __uint_as_float(u & 0xFFFF0000u);
  __syncthreads();
  float acc = 0.0f;
  for (int j = 0; j < 256; j++) acc = fmaf(gsh[j], W2[(256 + j) * 256 + t], acc);
  gterm[b * 256 + t] = acc;
}

// GEMM2 (MFMA, split-bf16) + fused epilogue:
// score[r] = sigmoid( sum_c gelu((H@w2top)[r,c] + gterm[b,c]) * w3[c] ) * mask_new
__global__ __launch_bounds__(256, 2) void gemm2_mfma(const uint32_t* __restrict__ Hp,
                                                     const ushort* __restrict__ w2hT,
                                                     const ushort* __restrict__ w2lT,
                                                     const float* __restrict__ gterm,
                                                     const float* __restrict__ w3,
                                                     const float* __restrict__ amask,
                                                     float* __restrict__ score) {
  __shared__ float sbuf[128][2];
  const int l = threadIdx.x & 63;
  const int wid = threadIdx.x >> 6;
  const int wm = wid >> 1, wn = wid & 1;
  const int lr = l & 15;
  const int g  = l >> 4;
  const int row0 = blockIdx.x * 128;
  const int b = row0 >> 9;

  f32x4 acc[4][8];
#pragma unroll
  for (int mt = 0; mt < 4; mt++)
#pragma unroll
    for (int nt = 0; nt < 8; nt++) acc[mt][nt] = (f32x4)0.0f;

  // A base: lane row = lr within tile; u32 idx = q*1024 + c*4 + sub
  const uint32_t* ab = Hp + (size_t)(((row0 + wm * 64) >> 2) + (lr >> 2)) * 1024 + (lr & 3) + g * 32;
  const ushort* bhb = w2hT + (size_t)(wn * 128 + lr) * 256 + g * 8;
  const ushort* blb = w2lT + (size_t)(wn * 128 + lr) * 256 + g * 8;

  for (int kt = 0; kt < 8; kt++) {
    const int ko = kt * 32;
    bf16x8 ah[4], al[4];
#pragma unroll
    for (int mt = 0; mt < 4; mt++) {
      const uint32_t* ap = ab + (size_t)mt * 4096 + kt * 128;
      uint32_t u[8];
#pragma unroll
      for (int j = 0; j < 8; j++) u[j] = ap[j * 4];
      BF8 H, L;
#pragma unroll
      for (int p = 0; p < 4; p++) {
        H.u[p] = (u[2 * p] & 0xFFFFu) | (u[2 * p + 1] << 16);
        L.u[p] = (u[2 * p] >> 16) | (u[2 * p + 1] & 0xFFFF0000u);
      }
      ah[mt] = H.v; al[mt] = L.v;
    }
#pragma unroll
    for (int nt = 0; nt < 8; nt++) {
      const bf16x8 bh = *(const bf16x8*)(bhb + (size_t)nt * 16 * 256 + ko);
      const bf16x8 bl = *(const bf16x8*)(blb + (size_t)nt * 16 * 256 + ko);
#pragma unroll
      for (int mt = 0; mt < 4; mt++) {
        acc[mt][nt] = __builtin_amdgcn_mfma_f32_16x16x32_bf16(ah[mt], bh, acc[mt][nt], 0, 0, 0);
        acc[mt][nt] = __builtin_amdgcn_mfma_f32_16x16x32_bf16(al[mt], bh, acc[mt][nt], 0, 0, 0);
        acc[mt][nt] = __builtin_amdgcn_mfma_f32_16x16x32_bf16(ah[mt], bl, acc[mt][nt], 0, 0, 0);
      }
    }
  }

  // epilogue: gelu(acc + gterm)*w3, reduce over 256 cols -> sigmoid*mask
  float s[4][4];
#pragma unroll
  for (int mt = 0; mt < 4; mt++)
#pragma unroll
    for (int r = 0; r < 4; r++) s[mt][r] = 0.0f;

#pragma unroll
  for (int nt = 0; nt < 8; nt++) {
    const int c = wn * 128 + nt * 16 + lr;
    const float gt = gterm[b * 256 + c];
    const float w3v = w3[c];
#pragma unroll
    for (int mt = 0; mt < 4; mt++)
#pragma unroll
      for (int r = 0; r < 4; r++)
        s[mt][r] = fmaf(gelu_exact(acc[mt][nt][r] + gt), w3v, s[mt][r]);
  }
#pragma unroll
  for (int mt = 0; mt < 4; mt++)
#pragma unroll
    for (int r = 0; r < 4; r++) {
#pragma unroll
      for (int m = 1; m < 16; m <<= 1) s[mt][r] += __shfl_xor(s[mt][r], m);
      if (lr == 0) sbuf[wm * 64 + mt * 16 + g * 4 + r][wn] = s[mt][r];
    }
  __syncthreads();
  const int t = threadIdx.x;
  if (t < 128) {
    const float ssum = sbuf[t][0] + sbuf[t][1];
    const int R = row0 + t;
    const int n = R & 511;
    const float mk = (n < 511) ? amask[(R >> 9) * 512 + n + 1] : 0.0f;
    score[R] = mk / (1.0f + expf(-ssum));
  }
}

// perturbed top-k (JAX partitionable threefry)
__global__ __launch_bounds__(256) void topk_kernel(const float* __restrict__ score,
                                                   int* __restrict__ counts) {
  const int lane = threadIdx.x & 63;
  const int wid = threadIdx.x >> 6;
  const int p = blockIdx.x * 4 + wid;   // b*500 + s
  const int b = p / 500;
  const uint32_t ibase = (uint32_t)p * 512u;
  const float* sc = score + b * 512;

  float v[8];
#pragma unroll
  for (int j = 0; j < 8; j++) {
    const int n = (j << 6) + lane;
    const uint2 o = threefry2x32(0u, ibase + (uint32_t)n);
    const uint32_t bits = o.x ^ o.y;
    const float nz = 1.41421356f * erfinv_f(bits_to_u(bits));
    v[j] = sc[n] + nz * 0.05f;
  }
  int idx[4];
  top4_wave(v, lane, idx);
  sort4(idx);
  if (lane == 0) {
    const int base = b * (T_K * T_N);
#pragma unroll
    for (int k = 0; k < 4; k++)
      atomicAdd(&counts[base + k * 512 + idx[k]], 1);
  }
}

// out[b,1+k,:] = (counts[b,k,:]/500) @ x[b,:,:]
__global__ __launch_bounds__(256) void select_kernel(const int* __restrict__ counts,
                                                     const float* __restrict__ x,
                                                     float* __restrict__ out) {
  __shared__ float cnt[4][512];
  __shared__ int list[512];
  __shared__ int nlist;
  const int b = blockIdx.x;
  const int t = threadIdx.x;
  if (t == 0) nlist = 0;
  __syncthreads();
  for (int l = t; l < 512; l += 256) {
    const int base = b * 2048 + l;
    const int c0 = counts[base];
    const int c1 = counts[base + 512];
    const int c2 = counts[base + 1024];
    const int c3 = counts[base + 1536];
    cnt[0][l] = (float)c0 * (1.0f / 500.0f);
    cnt[1][l] = (float)c1 * (1.0f / 500.0f);
    cnt[2][l] = (float)c2 * (1.0f / 500.0f);
    cnt[3][l] = (float)c3 * (1.0f / 500.0f);
    if ((c0 | c1 | c2 | c3) != 0) {
      const int pos = atomicAdd(&nlist, 1);
      list[pos] = l;
    }
  }
  __syncthreads();
  const int L = nlist;
  float a0[4] = {0.f, 0.f, 0.f, 0.f};
  float a1[4] = {0.f, 0.f, 0.f, 0.f};
  for (int e = 0; e < L; e++) {
    const int l = list[e];
    const float x0 = x[((size_t)b * 512 + l) * 512 + t];
    const float x1 = x[((size_t)b * 512 + l) * 512 + t + 256];
#pragma unroll
    for (int k = 0; k < 4; k++) {
      const float c = cnt[k][l];
      a0[k] = fmaf(c, x0, a0[k]);
      a1[k] = fmaf(c, x1, a1[k]);
    }
  }
#pragma unroll
  for (int k = 0; k < 4; k++) {
    out[(size_t)b * 2560 + (k + 1) * 512 + t] = a0[k];
    out[(size_t)b * 2560 + (k + 1) * 512 + t + 256] = a1[k];
  }
}

// ---------------- launcher ----------------
extern "C" void kernel_launch(void* const* d_in, const int* in_sizes, int n_in,
                              void* d_out, int out_size, void* d_ws, size_t ws_size,
                              hipStream_t stream) {
  const float* x     = (const float*)d_in[0];
  const int*   ids   = (const int*)d_in[1];
  const float* amask = (const float*)d_in[2];
  const float* lnw   = (const float*)d_in[3];
  const float* lnb   = (const float*)d_in[4];
  const float* w1    = (const float*)d_in[5];
  const float* b1    = (const float*)d_in[6];
  const float* w2    = (const float*)d_in[7];
  const float* w3    = (const float*)d_in[8];
  float* out = (float*)d_out;
  char* ws = (char*)d_ws;

  uint32_t* Hp     = (uint32_t*)(ws + OFF_HP);
  ushort*   w1hT   = (ushort*)(ws + OFF_W1HT);
  ushort*   w1lT   = (ushort*)(ws + OFF_W1LT);
  ushort*   w2hT   = (ushort*)(ws + OFF_W2HT);
  ushort*   w2lT   = (ushort*)(ws + OFF_W2LT);
  float2*   rowstat= (float2*)(ws + OFF_ROWSTAT);
  float*    uvec   = (float*)(ws + OFF_U);
  float*    vvec   = (float*)(ws + OFF_V);
  float*    gterm  = (float*)(ws + OFF_GTERM);
  float*    score  = (float*)(ws + OFF_SCORE);
  int*      clspos = (int*)(ws + OFF_CLSPOS);
  int*      counts = (int*)(ws + OFF_COUNTS);   // overlays Hp (dead by then)

  rowstats_kernel<<<16384, 256, 0, stream>>>(x, rowstat);
  prep_kernel<<<256, 256, 0, stream>>>(w1, lnw, w2, w1hT, w1lT, w2hT, w2lT);
  uv_kernel<<<1, 256, 0, stream>>>(w1, lnw, lnb, uvec, vvec);
  clspos_kernel<<<128, 64, 0, stream>>>(ids, x, clspos, out);
  gemm1_mfma<<<512, 256, 0, stream>>>(x, w1hT, w1lT, rowstat, uvec, vvec, b1, Hp);
  gterm_kernel<<<128, 256, 0, stream>>>(Hp, w2, clspos, gterm);
  gemm2_mfma<<<512, 256, 0, stream>>>(Hp, w2hT, w2lT, gterm, w3, amask, score);
  hipMemsetAsync(counts, 0, 128 * 4 * 512 * sizeof(int), stream);
  topk_kernel<<<16000, 256, 0, stream>>>(score, counts);
  select_kernel<<<128, 256, 0, stream>>>(counts, x, out);
}

// Round 8
// 668.553 us; speedup vs baseline: 1.2509x; 1.0187x over previous
//
#include <hip/hip_runtime.h>
#include <stdint.h>

// problem dims
#define T_B 128
#define T_N 512
#define T_D 512
#define T_C 256
#define T_S 500
#define T_K 4

// workspace offsets (bytes)
#define OFF_HP       0ull            // 65536x256 u32 (hi|lo<<16), quad-row tiled, 64 MiB
#define OFF_W1HT     67108864ull     // 256x512 bf16 (w1p^T hi)
#define OFF_W1LT     67371008ull     // 256x512 bf16 (w1p^T lo)
#define OFF_W2HT     67633152ull     // 256x256 bf16 (w2top^T hi)
#define OFF_W2LT     67764224ull     // 256x256 bf16 (w2top^T lo)
#define OFF_ROWSTAT  67895296ull     // 65536 float2
#define OFF_U        68419584ull     // 256 f32
#define OFF_V        68420608ull     // 256 f32
#define OFF_GTERM    68421632ull     // 128x256 f32
#define OFF_SCORE    68552704ull     // 65536 f32
#define OFF_CLSPOS   68814848ull     // 128 i32
#define OFF_COUNTS   0ull            // overlays HP: used only after gemm2/gterm done

typedef __attribute__((ext_vector_type(8))) short bf16x8;
typedef __attribute__((ext_vector_type(4))) float f32x4;

union BF8 { uint32_t u[4]; bf16x8 v; };

// ---------------- device helpers ----------------
__device__ __forceinline__ float gelu_exact(float z) {
  return 0.5f * z * (1.0f + erff(z * 0.70710678118654752440f));
}

__device__ __forceinline__ uint32_t rne_bf16(float f) {
  uint32_t u = __float_as_uint(f);
  return (u + 0x7FFFu + ((u >> 16) & 1u)) >> 16;
}

// JAX threefry2x32, key = (0, 12345)
__device__ __forceinline__ uint2 threefry2x32(uint32_t x0, uint32_t x1) {
  const uint32_t k0 = 0u;
  const uint32_t k1 = 12345u;
  const uint32_t k2 = k0 ^ k1 ^ 0x1BD11BDAu;
  x0 += k0; x1 += k1;
#define TF_ROUND(r) { x0 += x1; x1 = (x1 << (r)) | (x1 >> (32 - (r))); x1 ^= x0; }
  TF_ROUND(13) TF_ROUND(15) TF_ROUND(26) TF_ROUND(6)
  x0 += k1; x1 += k2 + 1u;
  TF_ROUND(17) TF_ROUND(29) TF_ROUND(16) TF_ROUND(24)
  x0 += k2; x1 += k0 + 2u;
  TF_ROUND(13) TF_ROUND(15) TF_ROUND(26) TF_ROUND(6)
  x0 += k0; x1 += k1 + 3u;
  TF_ROUND(17) TF_ROUND(29) TF_ROUND(16) TF_ROUND(24)
  x0 += k1; x1 += k2 + 4u;
  TF_ROUND(13) TF_ROUND(15) TF_ROUND(26) TF_ROUND(6)
  x0 += k2; x1 += k0 + 5u;
#undef TF_ROUND
  return make_uint2(x0, x1);
}

__device__ __forceinline__ void sort4(int a[4]) {
#define CS(x, y) { int lo = min(a[x], a[y]); int hi = max(a[x], a[y]); a[x] = lo; a[y] = hi; }
  CS(0, 1) CS(2, 3) CS(0, 2) CS(1, 3) CS(1, 2)
#undef CS
}

// ---------------- kernels ----------------

__global__ __launch_bounds__(256) void rowstats_kernel(const float* __restrict__ x,
                                                       float2* __restrict__ rowstat) {
  const int lane = threadIdx.x & 63;
  const int row = blockIdx.x * 4 + (threadIdx.x >> 6);
  const float* xr = x + (size_t)row * 512;
  float vals[8];
  float s = 0.0f;
#pragma unroll
  for (int j = 0; j < 8; j++) { vals[j] = xr[j * 64 + lane]; s += vals[j]; }
#pragma unroll
  for (int m = 1; m < 64; m <<= 1) s += __shfl_xor(s, m);
  const float mu = s * (1.0f / 512.0f);
  float d2 = 0.0f;
#pragma unroll
  for (int j = 0; j < 8; j++) { float d = vals[j] - mu; d2 = fmaf(d, d, d2); }
#pragma unroll
  for (int m = 1; m < 64; m <<= 1) d2 += __shfl_xor(d2, m);
  const float var = d2 * (1.0f / 512.0f);
  if (lane == 0) rowstat[row] = make_float2(mu, rsqrtf(var + 1e-5f));
}

// split + transpose weights: w1hT/w1lT[c][d] = split(lnw[d]*w1[d][c]); w2hT/w2lT[c][k] = split(w2[k][c])
__global__ __launch_bounds__(256) void prep_kernel(const float* __restrict__ w1,
                                                   const float* __restrict__ lnw,
                                                   const float* __restrict__ w2,
                                                   ushort* __restrict__ w1hT,
                                                   ushort* __restrict__ w1lT,
                                                   ushort* __restrict__ w2hT,
                                                   ushort* __restrict__ w2lT) {
  const int c = blockIdx.x;
  const int t = threadIdx.x;
#pragma unroll
  for (int it = 0; it < 2; it++) {
    const int d = t + it * 256;
    const float f = lnw[d] * w1[d * 256 + c];
    const uint32_t hi = rne_bf16(f);
    const float lo = f - __uint_as_float(hi << 16);
    w1hT[c * 512 + d] = (ushort)hi;
    w1lT[c * 512 + d] = (ushort)rne_bf16(lo);
  }
  {
    const float f = w2[t * 256 + c];   // top half of w2: k = t < 256
    const uint32_t hi = rne_bf16(f);
    const float lo = f - __uint_as_float(hi << 16);
    w2hT[c * 256 + t] = (ushort)hi;
    w2lT[c * 256 + t] = (ushort)rne_bf16(lo);
  }
}

__global__ __launch_bounds__(256) void uv_kernel(const float* __restrict__ w1,
                                                 const float* __restrict__ lnw,
                                                 const float* __restrict__ lnb,
                                                 float* __restrict__ uvec,
                                                 float* __restrict__ vvec) {
  const int c = threadIdx.x;
  float u = 0.0f, v = 0.0f;
  for (int d = 0; d < 512; d++) {
    const float w = w1[d * 256 + c];
    u = fmaf(lnw[d], w, u);
    v = fmaf(lnb[d], w, v);
  }
  uvec[c] = u;
  vvec[c] = v;
}

__global__ __launch_bounds__(64) void clspos_kernel(const int* __restrict__ ids,
                                                    const float* __restrict__ x,
                                                    int* __restrict__ cls_pos,
                                                    float* __restrict__ out) {
  const int b = blockIdx.x;
  const int lane = threadIdx.x;
  unsigned long long best = 0ull;
#pragma unroll
  for (int j = 0; j < 8; j++) {
    const int n = j * 64 + lane;
    const unsigned v = (unsigned)ids[b * 512 + n];
    const unsigned long long key = ((unsigned long long)v << 32) | (unsigned)(511 - n);
    best = key > best ? key : best;
  }
#pragma unroll
  for (int m = 1; m < 64; m <<= 1) {
    const unsigned long long o = __shfl_xor(best, m);
    best = o > best ? o : best;
  }
  const int n = 511 - (int)(best & 0xFFFFFFFFu);
  if (lane == 0) cls_pos[b] = n;
  const float* xr = x + ((size_t)b * 512 + n) * 512;
  float* orow = out + (size_t)b * 2560;
#pragma unroll
  for (int j = 0; j < 8; j++) orow[j * 64 + lane] = xr[j * 64 + lane];
}

// GEMM1 (MFMA, split-bf16): acc = x @ W1p; z = rstd*(acc - mu*u) + v + b1; Hp = split(gelu(z))
// grid 1024 blocks x 256 thr; block tile 64 rows x 256 cols; waves 2x2 (wm, wn), mt=2
__global__ __launch_bounds__(256, 3) void gemm1_mfma(const float* __restrict__ x,
                                                     const ushort* __restrict__ w1hT,
                                                     const ushort* __restrict__ w1lT,
                                                     const float2* __restrict__ rowstat,
                                                     const float* __restrict__ uvec,
                                                     const float* __restrict__ vvec,
                                                     const float* __restrict__ b1,
                                                     uint32_t* __restrict__ Hp) {
  const int l = threadIdx.x & 63;
  const int wid = threadIdx.x >> 6;
  const int wm = wid >> 1, wn = wid & 1;
  const int lr = l & 15;
  const int g  = l >> 4;
  const int row0 = blockIdx.x * 64;

  f32x4 acc[2][8];
#pragma unroll
  for (int mt = 0; mt < 2; mt++)
#pragma unroll
    for (int nt = 0; nt < 8; nt++) acc[mt][nt] = (f32x4)0.0f;

  const float* xb = x + (size_t)(row0 + wm * 32 + lr) * 512 + g * 8;
  const ushort* bhb = w1hT + (size_t)(wn * 128 + lr) * 512 + g * 8;
  const ushort* blb = w1lT + (size_t)(wn * 128 + lr) * 512 + g * 8;

  for (int kt = 0; kt < 16; kt++) {
    const int ko = kt * 32;
    bf16x8 ah[2], al[2];
#pragma unroll
    for (int mt = 0; mt < 2; mt++) {
      const float4 f0 = *(const float4*)(xb + (size_t)mt * 16 * 512 + ko);
      const float4 f1 = *(const float4*)(xb + (size_t)mt * 16 * 512 + ko + 4);
      float f[8] = {f0.x, f0.y, f0.z, f0.w, f1.x, f1.y, f1.z, f1.w};
      BF8 H, L;
#pragma unroll
      for (int p = 0; p < 4; p++) {
        const uint32_t u0 = __float_as_uint(f[2 * p]);
        const uint32_t u1 = __float_as_uint(f[2 * p + 1]);
        H.u[p] = (u0 >> 16) | (u1 & 0xFFFF0000u);                 // trunc-hi pair
        const float l0 = f[2 * p]     - __uint_as_float(u0 & 0xFFFF0000u);
        const float l1 = f[2 * p + 1] - __uint_as_float(u1 & 0xFFFF0000u);
        L.u[p] = rne_bf16(l0) | (rne_bf16(l1) << 16);             // rne-lo pair
      }
      ah[mt] = H.v; al[mt] = L.v;
    }
#pragma unroll
    for (int nt = 0; nt < 8; nt++) {
      const bf16x8 bh = *(const bf16x8*)(bhb + (size_t)nt * 16 * 512 + ko);
      const bf16x8 bl = *(const bf16x8*)(blb + (size_t)nt * 16 * 512 + ko);
#pragma unroll
      for (int mt = 0; mt < 2; mt++) {
        acc[mt][nt] = __builtin_amdgcn_mfma_f32_16x16x32_bf16(ah[mt], bh, acc[mt][nt], 0, 0, 0);
        acc[mt][nt] = __builtin_amdgcn_mfma_f32_16x16x32_bf16(al[mt], bh, acc[mt][nt], 0, 0, 0);
        acc[mt][nt] = __builtin_amdgcn_mfma_f32_16x16x32_bf16(ah[mt], bl, acc[mt][nt], 0, 0, 0);
      }
    }
  }

  // epilogue: LN fold + gelu + split-store (4 rows per dwordx4)
#pragma unroll
  for (int mt = 0; mt < 2; mt++) {
    const int Rb = row0 + wm * 32 + mt * 16 + g * 4;   // 4 consecutive rows Rb..Rb+3
    float2 st[4];
#pragma unroll
    for (int r = 0; r < 4; r++) st[r] = rowstat[Rb + r];
#pragma unroll
    for (int nt = 0; nt < 8; nt++) {
      const int c = wn * 128 + nt * 16 + lr;
      const float uu = uvec[c];
      const float vvb = vvec[c] + b1[c];
      uint32_t pk[4];
#pragma unroll
      for (int r = 0; r < 4; r++) {
        const float z = st[r].y * (acc[mt][nt][r] - st[r].x * uu) + vvb;
        const float gg = gelu_exact(z);
        const uint32_t ug = __float_as_uint(gg);
        const uint32_t hi = ug >> 16;                              // trunc-hi
        const float lo = gg - __uint_as_float(ug & 0xFFFF0000u);
        pk[r] = hi | (rne_bf16(lo) << 16);
      }
      uint32_t* dst = Hp + (size_t)(Rb >> 2) * 1024 + c * 4;
      *(uint4*)dst = make_uint4(pk[0], pk[1], pk[2], pk[3]);
    }
  }
}

// gterm[b,c] = h[b,cls_pos[b],:] @ w2[256:512, c]   (h reconstructed = hi + lo)
__global__ __launch_bounds__(256) void gterm_kernel(const uint32_t* __restrict__ Hp,
                                                    const float* __restrict__ W2,
                                                    const int* __restrict__ cls_pos,
                                                    float* __restrict__ gterm) {
  __shared__ float gsh[256];
  const int b = blockIdx.x;
  const int t = threadIdx.x;
  const int r = b * 512 + cls_pos[b];
  const uint32_t u = Hp[(size_t)(r >> 2) * 1024 + t * 4 + (r & 3)];
  gsh[t] = __uint_as_float((u & 0xFFFFu) << 16) + __uint_as_float(u & 0xFFFF0000u);
  __syncthreads();
  float acc = 0.0f;
  for (int j = 0; j < 256; j++) acc = fmaf(gsh[j], W2[(256 + j) * 256 + t], acc);
  gterm[b * 256 + t] = acc;
}

// GEMM2 (MFMA, split-bf16) + fused epilogue:
// score[r] = sigmoid( sum_c gelu((H@w2top)[r,c] + gterm[b,c]) * w3[c] ) * mask_new
// grid 1024 blocks, tile 64 rows, waves 2x2, mt=2
__global__ __launch_bounds__(256, 3) void gemm2_mfma(const uint32_t* __restrict__ Hp,
                                                     const ushort* __restrict__ w2hT,
                                                     const ushort* __restrict__ w2lT,
                                                     const float* __restrict__ gterm,
                                                     const float* __restrict__ w3,
                                                     const float* __restrict__ amask,
                                                     float* __restrict__ score) {
  __shared__ float sbuf[64][2];
  const int l = threadIdx.x & 63;
  const int wid = threadIdx.x >> 6;
  const int wm = wid >> 1, wn = wid & 1;
  const int lr = l & 15;
  const int g  = l >> 4;
  const int row0 = blockIdx.x * 64;
  const int b = row0 >> 9;

  f32x4 acc[2][8];
#pragma unroll
  for (int mt = 0; mt < 2; mt++)
#pragma unroll
    for (int nt = 0; nt < 8; nt++) acc[mt][nt] = (f32x4)0.0f;

  // A base: lane row = lr within tile; u32 idx = q*1024 + c*4 + sub
  const uint32_t* ab = Hp + (size_t)(((row0 + wm * 32) >> 2) + (lr >> 2)) * 1024 + (lr & 3) + g * 32;
  const ushort* bhb = w2hT + (size_t)(wn * 128 + lr) * 256 + g * 8;
  const ushort* blb = w2lT + (size_t)(wn * 128 + lr) * 256 + g * 8;

  for (int kt = 0; kt < 8; kt++) {
    const int ko = kt * 32;
    bf16x8 ah[2], al[2];
#pragma unroll
    for (int mt = 0; mt < 2; mt++) {
      const uint32_t* ap = ab + (size_t)mt * 4096 + kt * 128;
      uint32_t u[8];
#pragma unroll
      for (int j = 0; j < 8; j++) u[j] = ap[j * 4];
      BF8 H, L;
#pragma unroll
      for (int p = 0; p < 4; p++) {
        H.u[p] = (u[2 * p] & 0xFFFFu) | (u[2 * p + 1] << 16);
        L.u[p] = (u[2 * p] >> 16) | (u[2 * p + 1] & 0xFFFF0000u);
      }
      ah[mt] = H.v; al[mt] = L.v;
    }
#pragma unroll
    for (int nt = 0; nt < 8; nt++) {
      const bf16x8 bh = *(const bf16x8*)(bhb + (size_t)nt * 16 * 256 + ko);
      const bf16x8 bl = *(const bf16x8*)(blb + (size_t)nt * 16 * 256 + ko);
#pragma unroll
      for (int mt = 0; mt < 2; mt++) {
        acc[mt][nt] = __builtin_amdgcn_mfma_f32_16x16x32_bf16(ah[mt], bh, acc[mt][nt], 0, 0, 0);
        acc[mt][nt] = __builtin_amdgcn_mfma_f32_16x16x32_bf16(al[mt], bh, acc[mt][nt], 0, 0, 0);
        acc[mt][nt] = __builtin_amdgcn_mfma_f32_16x16x32_bf16(ah[mt], bl, acc[mt][nt], 0, 0, 0);
      }
    }
  }

  // epilogue: gelu(acc + gterm)*w3, reduce over 256 cols -> sigmoid*mask
  float s[2][4];
#pragma unroll
  for (int mt = 0; mt < 2; mt++)
#pragma unroll
    for (int r = 0; r < 4; r++) s[mt][r] = 0.0f;

#pragma unroll
  for (int nt = 0; nt < 8; nt++) {
    const int c = wn * 128 + nt * 16 + lr;
    const float gt = gterm[b * 256 + c];
    const float w3v = w3[c];
#pragma unroll
    for (int mt = 0; mt < 2; mt++)
#pragma unroll
      for (int r = 0; r < 4; r++)
        s[mt][r] = fmaf(gelu_exact(acc[mt][nt][r] + gt), w3v, s[mt][r]);
  }
#pragma unroll
  for (int mt = 0; mt < 2; mt++)
#pragma unroll
    for (int r = 0; r < 4; r++) {
#pragma unroll
      for (int m = 1; m < 16; m <<= 1) s[mt][r] += __shfl_xor(s[mt][r], m);
      if (lr == 0) sbuf[wm * 32 + mt * 16 + g * 4 + r][wn] = s[mt][r];
    }
  __syncthreads();
  const int t = threadIdx.x;
  if (t < 64) {
    const float ssum = sbuf[t][0] + sbuf[t][1];
    const int R = row0 + t;
    const int n = R & 511;
    const float mk = (n < 511) ? amask[(R >> 9) * 512 + n + 1] : 0.0f;
    score[R] = mk / (1.0f + expf(-ssum));
  }
}

// perturbed top-k (JAX partitionable threefry), branch-free erfinv, u64-key top-4
__global__ __launch_bounds__(256) void topk_kernel(const float* __restrict__ score,
                                                   int* __restrict__ counts) {
  const int lane = threadIdx.x & 63;
  const int wid = threadIdx.x >> 6;
  const int p = blockIdx.x * 4 + wid;   // b*500 + s
  const int b = p / 500;
  const uint32_t ibase = (uint32_t)p * 512u;
  const float* sc = score + b * 512;

  uint32_t hi[8];
#pragma unroll
  for (int j = 0; j < 8; j++) {
    const int n = (j << 6) + lane;
    const uint2 o = threefry2x32(0u, ibase + (uint32_t)n);
    const uint32_t bits = o.x ^ o.y;
    // JAX uniform(lo=nextafter(-1,0), hi=1)
    const float f = __uint_as_float((bits >> 9) | 0x3F800000u) - 1.0f;
    const float x = fmaxf(-0.99999994f, fmaf(f, 2.0f, -0.99999994f));
    // erfinv (Giles/XLA poly), branch-free: compute both polys, select
    const float t = fmaf(-x, x, 1.0f);                 // 1 - x^2
    const float w = -0.69314718056f * __log2f(t);      // -ln(1-x^2)
    const float wa = w - 2.5f;
    const float wb = sqrtf(w) - 3.0f;
    float pa = 2.81022636e-08f;
    pa = fmaf(pa, wa, 3.43273939e-07f);
    pa = fmaf(pa, wa, -3.5233877e-06f);
    pa = fmaf(pa, wa, -4.39150654e-06f);
    pa = fmaf(pa, wa, 0.00021858087f);
    pa = fmaf(pa, wa, -0.00125372503f);
    pa = fmaf(pa, wa, -0.00417768164f);
    pa = fmaf(pa, wa, 0.246640727f);
    pa = fmaf(pa, wa, 1.50140941f);
    float pb = -0.000200214257f;
    pb = fmaf(pb, wb, 0.000100950558f);
    pb = fmaf(pb, wb, 0.00134934322f);
    pb = fmaf(pb, wb, -0.00367342844f);
    pb = fmaf(pb, wb, 0.00573950773f);
    pb = fmaf(pb, wb, -0.0076224613f);
    pb = fmaf(pb, wb, 0.00943887047f);
    pb = fmaf(pb, wb, 1.00167406f);
    pb = fmaf(pb, wb, 2.83297682f);
    const float pp = (w < 5.0f) ? pa : pb;
    // val = score + 0.05*sqrt(2)*erfinv(u)
    const float val = fmaf(pp * x, 0.07071067812f, sc[n]);
    hi[j] = __float_as_uint(val + 1.0f);   // val in (-0.28,1.28) -> positive, order-preserving bits
  }

  int res[4];
#pragma unroll
  for (int it = 0; it < 4; it++) {
    // local argmax over 8 (strict > keeps lowest j = lowest n on ties)
    uint32_t bh = hi[0];
    int bl = 511 - lane;
#pragma unroll
    for (int j = 1; j < 8; j++) {
      const int loj = 511 - ((j << 6) + lane);
      if (hi[j] > bh) { bh = hi[j]; bl = loj; }
    }
    // butterfly max on packed key (value bits, 511-n): larger key = larger val, tie -> lower n
    unsigned long long k = ((unsigned long long)bh << 32) | (unsigned)bl;
#pragma unroll
    for (int m = 32; m >= 1; m >>= 1) {
      const unsigned long long ok = __shfl_xor(k, m);
      k = ok > k ? ok : k;
    }
    const int bn = 511 - (int)(k & 0xFFFFu);
    res[it] = bn;
    // invalidate winner
    if ((bn & 63) == lane) {
      const int jj = bn >> 6;
#pragma unroll
      for (int j = 0; j < 8; j++)
        if (j == jj) hi[j] = 0u;
    }
  }
  sort4(res);
  if (lane == 0) {
    const int base = b * (T_K * T_N);
#pragma unroll
    for (int kk = 0; kk < 4; kk++)
      atomicAdd(&counts[base + kk * 512 + res[kk]], 1);
  }
}

// out[b,1+k,:] = (counts[b,k,:]/500) @ x[b,:,:]
__global__ __launch_bounds__(256) void select_kernel(const int* __restrict__ counts,
                                                     const float* __restrict__ x,
                                                     float* __restrict__ out) {
  __shared__ float cnt[4][512];
  __shared__ int list[512];
  __shared__ int nlist;
  const int b = blockIdx.x;
  const int t = threadIdx.x;
  if (t == 0) nlist = 0;
  __syncthreads();
  for (int l = t; l < 512; l += 256) {
    const int base = b * 2048 + l;
    const int c0 = counts[base];
    const int c1 = counts[base + 512];
    const int c2 = counts[base + 1024];
    const int c3 = counts[base + 1536];
    cnt[0][l] = (float)c0 * (1.0f / 500.0f);
    cnt[1][l] = (float)c1 * (1.0f / 500.0f);
    cnt[2][l] = (float)c2 * (1.0f / 500.0f);
    cnt[3][l] = (float)c3 * (1.0f / 500.0f);
    if ((c0 | c1 | c2 | c3) != 0) {
      const int pos = atomicAdd(&nlist, 1);
      list[pos] = l;
    }
  }
  __syncthreads();
  const int L = nlist;
  float a0[4] = {0.f, 0.f, 0.f, 0.f};
  float a1[4] = {0.f, 0.f, 0.f, 0.f};
  for (int e = 0; e < L; e++) {
    const int l = list[e];
    const float x0 = x[((size_t)b * 512 + l) * 512 + t];
    const float x1 = x[((size_t)b * 512 + l) * 512 + t + 256];
#pragma unroll
    for (int k = 0; k < 4; k++) {
      const float c = cnt[k][l];
      a0[k] = fmaf(c, x0, a0[k]);
      a1[k] = fmaf(c, x1, a1[k]);
    }
  }
#pragma unroll
  for (int k = 0; k < 4; k++) {
    out[(size_t)b * 2560 + (k + 1) * 512 + t] = a0[k];
    out[(size_t)b * 2560 + (k + 1) * 512 + t + 256] = a1[k];
  }
}

// ---------------- launcher ----------------
extern "C" void kernel_launch(void* const* d_in, const int* in_sizes, int n_in,
                              void* d_out, int out_size, void* d_ws, size_t ws_size,
                              hipStream_t stream) {
  const float* x     = (const float*)d_in[0];
  const int*   ids   = (const int*)d_in[1];
  const float* amask = (const float*)d_in[2];
  const float* lnw   = (const float*)d_in[3];
  const float* lnb   = (const float*)d_in[4];
  const float* w1    = (const float*)d_in[5];
  const float* b1    = (const float*)d_in[6];
  const float* w2    = (const float*)d_in[7];
  const float* w3    = (const float*)d_in[8];
  float* out = (float*)d_out;
  char* ws = (char*)d_ws;

  uint32_t* Hp     = (uint32_t*)(ws + OFF_HP);
  ushort*   w1hT   = (ushort*)(ws + OFF_W1HT);
  ushort*   w1lT   = (ushort*)(ws + OFF_W1LT);
  ushort*   w2hT   = (ushort*)(ws + OFF_W2HT);
  ushort*   w2lT   = (ushort*)(ws + OFF_W2LT);
  float2*   rowstat= (float2*)(ws + OFF_ROWSTAT);
  float*    uvec   = (float*)(ws + OFF_U);
  float*    vvec   = (float*)(ws + OFF_V);
  float*    gterm  = (float*)(ws + OFF_GTERM);
  float*    score  = (float*)(ws + OFF_SCORE);
  int*      clspos = (int*)(ws + OFF_CLSPOS);
  int*      counts = (int*)(ws + OFF_COUNTS);   // overlays Hp (dead by then)

  rowstats_kernel<<<16384, 256, 0, stream>>>(x, rowstat);
  prep_kernel<<<256, 256, 0, stream>>>(w1, lnw, w2, w1hT, w1lT, w2hT, w2lT);
  uv_kernel<<<1, 256, 0, stream>>>(w1, lnw, lnb, uvec, vvec);
  clspos_kernel<<<128, 64, 0, stream>>>(ids, x, clspos, out);
  gemm1_mfma<<<1024, 256, 0, stream>>>(x, w1hT, w1lT, rowstat, uvec, vvec, b1, Hp);
  gterm_kernel<<<128, 256, 0, stream>>>(Hp, w2, clspos, gterm);
  gemm2_mfma<<<1024, 256, 0, stream>>>(Hp, w2hT, w2lT, gterm, w3, amask, score);
  hipMemsetAsync(counts, 0, 128 * 4 * 512 * sizeof(int), stream);
  topk_kernel<<<16000, 256, 0, stream>>>(score, counts);
  select_kernel<<<128, 256, 0, stream>>>(counts, x, out);
}